// Round 10
// baseline (191.748 us; speedup 1.0000x reference)
//
#include <hip/hip_runtime.h>
#include <math.h>

#define NPTS 8192
#define TPB  256          // threads per block, knn kernel
#define QPL  2            // queries per lane
#define TPM  256          // threads per block, merge/final kernels
#define QPB_M 32          // queries per merge block
#define NCHUNK 8          // split-chunks per merge block

// ---------------------------------------------------------------------------
// Forced v_max3_f32 forms (the C pattern was NOT folding: R9 showed
// ~113 instr/pair vs 64 expected -> compiler emitted and+max chains).
// ---------------------------------------------------------------------------
__device__ __forceinline__ float max3abs(float a, float b, float c) {
    float r;
    asm("v_max3_f32 %0, |%1|, |%2|, |%3|" : "=v"(r) : "v"(a), "v"(b), "v"(c));
    return r;
}
__device__ __forceinline__ float max3vaa(float m, float b, float c) {
    float r;
    asm("v_max3_f32 %0, %1, |%2|, |%3|" : "=v"(r) : "v"(m), "v"(b), "v"(c));
    return r;
}
__device__ __forceinline__ float max3v(float a, float b, float c) {
    float r;
    asm("v_max3_f32 %0, %1, %2, %3" : "=v"(r) : "v"(a), "v"(b), "v"(c));
    return r;
}

__device__ __forceinline__ float fmax3(float a, float b, float c) {
    return fmaxf(fmaxf(a, b), c);
}

// 32-dim Chebyshev distance: 32 subs + 16 forced max3/max ops.
__device__ __forceinline__ float cheb32_pair(const float* __restrict__ q,
                                             const float* __restrict__ p) {
    float s[32];
    #pragma unroll
    for (int k = 0; k < 32; ++k) s[k] = q[k] - p[k];
    float l[10];
    #pragma unroll
    for (int g = 0; g < 10; ++g) l[g] = max3abs(s[3*g], s[3*g+1], s[3*g+2]);
    float c3 = max3vaa(l[9], s[30], s[31]);
    float c0 = max3v(l[0], l[1], l[2]);
    float c1 = max3v(l[3], l[4], l[5]);
    float c2 = max3v(l[6], l[7], l[8]);
    return fmaxf(max3v(c0, c1, c2), c3);
}

// Branchless sorted-descending top-4 insert with index payload on levels 0-2.
__device__ __forceinline__ void ins4p(float d, int di,
    float& t0, float& t1, float& t2, float& t3,
    int& i0, int& i1, int& i2)
{
    bool c0 = d > t0;
    float v1 = fminf(t0, d); int j1 = c0 ? i0 : di;
    t0 = fmaxf(t0, d);       i0 = c0 ? di : i0;
    bool c1 = v1 > t1;
    float v2 = fminf(t1, v1); int j2 = c1 ? i1 : j1;
    t1 = fmaxf(t1, v1);       i1 = c1 ? j1 : i1;
    bool c2 = v2 > t2;
    float v3 = fminf(t2, v2);
    t2 = fmaxf(t2, v2);       i2 = c2 ? j2 : i2;
    t3 = fmaxf(t3, v3);
}

__device__ double digamma_d(double x) {
    double r = 0.0;
    while (x < 6.0) { r -= 1.0 / x; x += 1.0; }
    double f = 1.0 / (x * x);
    double t = f * (1.0/12.0 - f * (1.0/120.0 - f * (1.0/252.0 - f * (1.0/240.0 - f * (1.0/132.0)))));
    return r + log(x) - 0.5 / x - t;
}

__device__ __forceinline__ void load_query(float* qv, const float* __restrict__ x,
                                           const float* __restrict__ y, int q)
{
    const float4* qx4 = reinterpret_cast<const float4*>(x) + (size_t)q * 4;
    const float4* qy4 = reinterpret_cast<const float4*>(y) + (size_t)q * 4;
    #pragma unroll
    for (int i = 0; i < 4; ++i) {
        float4 v = qx4[i];
        qv[4*i+0] = v.x; qv[4*i+1] = v.y; qv[4*i+2] = v.z; qv[4*i+3] = v.w;
        float4 w = qy4[i];
        qv[16+4*i+0] = w.x; qv[16+4*i+1] = w.y; qv[16+4*i+2] = w.z; qv[16+4*i+3] = w.w;
    }
}

typedef const __attribute__((address_space(4))) float cfloat;

// ---------------------------------------------------------------------------
// K1: per-query partial top-4 (values) + top-3 (indices) of joint Chebyshev
// distance over a point split. grid = (NPTS/(TPB*QPL), Sk) = 2048 blocks.
// Points are wave-uniform -> fetched via the SCALAR pipe (addrspace(4) cast
// selects s_load for uniform addresses): no LDS, no __syncthreads, VALU-only.
// ---------------------------------------------------------------------------
__global__ __launch_bounds__(TPB, 2) void knn_part_kernel(
    const float* __restrict__ x, const float* __restrict__ y,
    float4* __restrict__ part_v, ushort4* __restrict__ part_i, int pps)
{
    cfloat* px = (cfloat*)(unsigned long long)(const void*)x;
    cfloat* py = (cfloat*)(unsigned long long)(const void*)y;

    float qv[QPL][32];
    float t0[QPL], t1[QPL], t2[QPL], t3[QPL];
    int   i0[QPL], i1[QPL], i2[QPL];
    #pragma unroll
    for (int u = 0; u < QPL; ++u) {
        load_query(qv[u], x, y, blockIdx.x * (TPB * QPL) + threadIdx.x + u * TPB);
        t0[u] = t1[u] = t2[u] = t3[u] = -1.0f;
        i0[u] = i1[u] = i2[u] = 0;
    }

    const int j0 = blockIdx.y * pps;
    #pragma unroll 2
    for (int j = j0; j < j0 + pps; ++j) {
        cfloat* fx = px + (size_t)j * 16;   // wave-uniform -> s_load_dwordx16
        cfloat* fy = py + (size_t)j * 16;
        float p[32];
        #pragma unroll
        for (int i = 0; i < 16; ++i) { p[i] = fx[i]; p[16 + i] = fy[i]; }
        #pragma unroll
        for (int u = 0; u < QPL; ++u) {
            float m = cheb32_pair(qv[u], p);
            ins4p(m, j, t0[u], t1[u], t2[u], t3[u], i0[u], i1[u], i2[u]);
        }
    }
    #pragma unroll
    for (int u = 0; u < QPL; ++u) {
        int q = blockIdx.x * (TPB * QPL) + threadIdx.x + u * TPB;
        part_v[(size_t)blockIdx.y * NPTS + q] = make_float4(t0[u], t1[u], t2[u], t3[u]);
        part_i[(size_t)blockIdx.y * NPTS + q] =
            make_ushort4((unsigned short)i0[u], (unsigned short)i1[u],
                         (unsigned short)i2[u], 0);
    }
}

// ---------------------------------------------------------------------------
// K2 (fused): two-stage merge of Sk partials + exact candidate count + digamma.
// Every point outside the joint top-3 has d_joint <= t3 = r, hence dx <= r and
// dy <= r bit-exactly (marginal max over a subset of the same f32 values), so
// nx = NPTS - #{top-3 candidates with dx > r}. Index-less 4th values are safe:
// a split's top-3 are inserted before its 4th by the same thread.
// ---------------------------------------------------------------------------
__global__ __launch_bounds__(TPM) void merge_check_kernel(
    const float4* __restrict__ part_v, const ushort4* __restrict__ part_i,
    const float* __restrict__ x, const float* __restrict__ y,
    double* __restrict__ dig, int S)
{
    __shared__ float4  sv[NCHUNK][QPB_M];
    __shared__ ushort4 si[NCHUNK][QPB_M];
    const int ql = threadIdx.x & (QPB_M - 1);
    const int ck = threadIdx.x / QPB_M;          // 0..7
    const int q  = blockIdx.x * QPB_M + ql;
    const int cl = S / NCHUNK;

    float t0=-1.f,t1=-1.f,t2=-1.f,t3=-1.f;
    int i0=0,i1=0,i2=0;
    for (int k = 0; k < cl; ++k) {
        const int s = ck * cl + k;
        float4  v  = part_v[(size_t)s * NPTS + q];
        ushort4 id = part_i[(size_t)s * NPTS + q];
        ins4p(v.x, id.x, t0,t1,t2,t3, i0,i1,i2);
        ins4p(v.y, id.y, t0,t1,t2,t3, i0,i1,i2);
        ins4p(v.z, id.z, t0,t1,t2,t3, i0,i1,i2);
        ins4p(v.w, 0,    t0,t1,t2,t3, i0,i1,i2);  // 4th: value-only
    }
    sv[ck][ql] = make_float4(t0, t1, t2, t3);
    si[ck][ql] = make_ushort4((unsigned short)i0, (unsigned short)i1,
                              (unsigned short)i2, 0);
    __syncthreads();

    if (ck == 0) {
        #pragma unroll
        for (int c = 1; c < NCHUNK; ++c) {
            float4  v  = sv[c][ql];
            ushort4 id = si[c][ql];
            ins4p(v.x, id.x, t0,t1,t2,t3, i0,i1,i2);
            ins4p(v.y, id.y, t0,t1,t2,t3, i0,i1,i2);
            ins4p(v.z, id.z, t0,t1,t2,t3, i0,i1,i2);
            ins4p(v.w, 0,    t0,t1,t2,t3, i0,i1,i2);
        }
        const float rq = t3 - 1e-15f;  // == t3 bit-exact in f32 (reference fidelity)

        float qv[32];
        load_query(qv, x, y, q);

        float vals[3] = { t0, t1, t2 };
        int   idxs[3] = { i0, i1, i2 };
        int missx = 0, missy = 0;
        #pragma unroll
        for (int k = 0; k < 3; ++k) {
            const int j = idxs[k];
            const float4* px4 = reinterpret_cast<const float4*>(x) + (size_t)j * 4;
            const float4* py4 = reinterpret_cast<const float4*>(y) + (size_t)j * 4;
            float mx = 0.0f, my = 0.0f;
            #pragma unroll
            for (int i = 0; i < 4; ++i) {
                float4 a = px4[i];
                mx = fmax3(mx, fmax3(fabsf(qv[4*i+0]-a.x), fabsf(qv[4*i+1]-a.y),
                                     fabsf(qv[4*i+2]-a.z)), fabsf(qv[4*i+3]-a.w));
                float4 b = py4[i];
                my = fmax3(my, fmax3(fabsf(qv[16+4*i+0]-b.x), fabsf(qv[16+4*i+1]-b.y),
                                     fabsf(qv[16+4*i+2]-b.z)), fabsf(qv[16+4*i+3]-b.w));
            }
            const bool act = vals[k] > rq;   // only strict-greater joints can miss
            missx += (act && (mx > rq)) ? 1 : 0;
            missy += (act && (my > rq)) ? 1 : 0;
        }
        const int nx = NPTS - missx;
        const int ny = NPTS - missy;
        dig[q] = digamma_d((double)nx) + digamma_d((double)ny);
    }
}

// ---------------------------------------------------------------------------
// K3: ans = psi(N) + psi(k) - mean(psi(nx)+psi(ny))
// (log/log2 terms of the reference cancel exactly in ans_x+ans_y-ans_xy)
// ---------------------------------------------------------------------------
__global__ __launch_bounds__(TPM) void final_kernel(
    const double* __restrict__ dig, float* __restrict__ out)
{
    __shared__ double sm[TPM];
    double s = 0.0;
    for (int i = threadIdx.x; i < NPTS; i += TPM) s += dig[i];
    sm[threadIdx.x] = s;
    __syncthreads();
    for (int w = TPM / 2; w > 0; w >>= 1) {
        if (threadIdx.x < w) sm[threadIdx.x] += sm[threadIdx.x + w];
        __syncthreads();
    }
    if (threadIdx.x == 0) {
        double ans = digamma_d((double)NPTS) + digamma_d(4.0) - sm[0] / (double)NPTS;
        out[0] = (float)ans;
    }
}

// ---------------------------------------------------------------------------
extern "C" void kernel_launch(void* const* d_in, const int* in_sizes, int n_in,
                              void* d_out, int out_size, void* d_ws, size_t ws_size,
                              hipStream_t stream)
{
    (void)in_sizes; (void)n_in; (void)out_size;
    const float* x = (const float*)d_in[0];
    const float* y = (const float*)d_in[1];
    float* out = (float*)d_out;

    // workspace: dig (NPTS f64) | part_v (Sk*NPTS float4) | part_i (Sk*NPTS ushort4)
    char* ws = (char*)d_ws;
    double* dig = (double*)ws;
    char*   p0  = ws + (size_t)NPTS * 8;     // 16B aligned

    int Sk = 128;
    auto need = [&](int sk) {
        return (size_t)(p0 - ws) + (size_t)sk * NPTS * 24;
    };
    while (Sk > 32 && need(Sk) > ws_size) Sk >>= 1;

    float4*  part_v = (float4*)p0;
    ushort4* part_i = (ushort4*)(p0 + (size_t)Sk * NPTS * 16);
    const int pps = NPTS / Sk;

    dim3 gridK(NPTS / (TPB * QPL), Sk);   // (16,128) = 2048 blocks = 8192 waves
    knn_part_kernel<<<gridK, TPB, 0, stream>>>(x, y, part_v, part_i, pps);
    merge_check_kernel<<<NPTS / QPB_M, TPM, 0, stream>>>(part_v, part_i, x, y, dig, Sk);
    final_kernel<<<1, TPM, 0, stream>>>(dig, out);
}

// Round 11
// 162.836 us; speedup vs baseline: 1.1775x; 1.1775x over previous
//
#include <hip/hip_runtime.h>
#include <math.h>

#define NPTS 8192
#define TPB  256          // threads per block, knn kernel
#define QPL  2            // queries per lane
#define TILE 64           // points staged per LDS tile (8 KB f32)
#define TPM  256          // threads per block, merge kernel
#define QPB_M 32          // queries per merge block
#define NCHUNK 8          // split-chunks per merge block

// ---------------------------------------------------------------------------
// Forced v_max3_f32 forms (C pattern does NOT fold: R9 ~113 instr/pair).
// R10-proven correct (absmax 0.0).
// ---------------------------------------------------------------------------
__device__ __forceinline__ float max3abs(float a, float b, float c) {
    float r;
    asm("v_max3_f32 %0, |%1|, |%2|, |%3|" : "=v"(r) : "v"(a), "v"(b), "v"(c));
    return r;
}
__device__ __forceinline__ float max3vaa(float m, float b, float c) {
    float r;
    asm("v_max3_f32 %0, %1, |%2|, |%3|" : "=v"(r) : "v"(m), "v"(b), "v"(c));
    return r;
}
__device__ __forceinline__ float max3v(float a, float b, float c) {
    float r;
    asm("v_max3_f32 %0, %1, %2, %3" : "=v"(r) : "v"(a), "v"(b), "v"(c));
    return r;
}
__device__ __forceinline__ float fmax3(float a, float b, float c) {
    return fmaxf(fmaxf(a, b), c);
}

// 32-dim Chebyshev: 32 subs + 16 forced max3/max ops = 48 VALU.
__device__ __forceinline__ float cheb32_pair(const float* __restrict__ q,
                                             const float* __restrict__ p) {
    float s[32];
    #pragma unroll
    for (int k = 0; k < 32; ++k) s[k] = q[k] - p[k];
    float l[10];
    #pragma unroll
    for (int g = 0; g < 10; ++g) l[g] = max3abs(s[3*g], s[3*g+1], s[3*g+2]);
    float c3 = max3vaa(l[9], s[30], s[31]);
    float c0 = max3v(l[0], l[1], l[2]);
    float c1 = max3v(l[3], l[4], l[5]);
    float c2 = max3v(l[6], l[7], l[8]);
    return fmaxf(max3v(c0, c1, c2), c3);
}

// Branchless sorted-descending top-4 insert with index payload on levels 0-2.
__device__ __forceinline__ void ins4p(float d, int di,
    float& t0, float& t1, float& t2, float& t3,
    int& i0, int& i1, int& i2)
{
    bool c0 = d > t0;
    float v1 = fminf(t0, d); int j1 = c0 ? i0 : di;
    t0 = fmaxf(t0, d);       i0 = c0 ? di : i0;
    bool c1 = v1 > t1;
    float v2 = fminf(t1, v1); int j2 = c1 ? i1 : j1;
    t1 = fmaxf(t1, v1);       i1 = c1 ? j1 : i1;
    bool c2 = v2 > t2;
    float v3 = fminf(t2, v2);
    t2 = fmaxf(t2, v2);       i2 = c2 ? j2 : i2;
    t3 = fmaxf(t3, v3);
}

__device__ double digamma_d(double x) {
    double r = 0.0;
    while (x < 6.0) { r -= 1.0 / x; x += 1.0; }
    double f = 1.0 / (x * x);
    double t = f * (1.0/12.0 - f * (1.0/120.0 - f * (1.0/252.0 - f * (1.0/240.0 - f * (1.0/132.0)))));
    return r + log(x) - 0.5 / x - t;
}

// Cooperative stage of TILE points (x:16 + y:16 floats) into LDS.
__device__ __forceinline__ void stage_tile(
    float4* pts4, const float* __restrict__ x, const float* __restrict__ y, int jt)
{
    #pragma unroll
    for (int i = 0; i < (TILE * 8) / TPB; ++i) {
        int li = i * TPB + threadIdx.x;
        int pt = li >> 3, c = li & 7;
        const float4* src = (c < 4)
            ? reinterpret_cast<const float4*>(x) + (size_t)(jt + pt) * 4 + c
            : reinterpret_cast<const float4*>(y) + (size_t)(jt + pt) * 4 + (c - 4);
        pts4[li] = *src;
    }
}

__device__ __forceinline__ void load_query(float* qv, const float* __restrict__ x,
                                           const float* __restrict__ y, int q)
{
    const float4* qx4 = reinterpret_cast<const float4*>(x) + (size_t)q * 4;
    const float4* qy4 = reinterpret_cast<const float4*>(y) + (size_t)q * 4;
    #pragma unroll
    for (int i = 0; i < 4; ++i) {
        float4 v = qx4[i];
        qv[4*i+0] = v.x; qv[4*i+1] = v.y; qv[4*i+2] = v.z; qv[4*i+3] = v.w;
        float4 w = qy4[i];
        qv[16+4*i+0] = w.x; qv[16+4*i+1] = w.y; qv[16+4*i+2] = w.z; qv[16+4*i+3] = w.w;
    }
}

// ---------------------------------------------------------------------------
// K1: per-query partial top-4 (values) + top-3 (indices) of joint Chebyshev
// distance over a point split. R9-proven LDS-staged shape + forced-max3 cheb.
// grid = (NPTS/(TPB*QPL), Sk) = 2048 blocks = 8192 waves.
// ---------------------------------------------------------------------------
__global__ __launch_bounds__(TPB, 2) void knn_part_kernel(
    const float* __restrict__ x, const float* __restrict__ y,
    float4* __restrict__ part_v, ushort4* __restrict__ part_i, int pps)
{
    __shared__ float4 pts4[TILE * 8];
    float qv[QPL][32];
    float t0[QPL], t1[QPL], t2[QPL], t3[QPL];
    int   i0[QPL], i1[QPL], i2[QPL];
    #pragma unroll
    for (int u = 0; u < QPL; ++u) {
        load_query(qv[u], x, y, blockIdx.x * (TPB * QPL) + threadIdx.x + u * TPB);
        t0[u] = t1[u] = t2[u] = t3[u] = -1.0f;
        i0[u] = i1[u] = i2[u] = 0;
    }

    const int j0 = blockIdx.y * pps;
    for (int jt = j0; jt < j0 + pps; jt += TILE) {
        stage_tile(pts4, x, y, jt);
        __syncthreads();
        #pragma unroll 2
        for (int jj = 0; jj < TILE; ++jj) {
            const float4* pj = &pts4[jj * 8];
            float p[32];
            #pragma unroll
            for (int i = 0; i < 8; ++i) {
                float4 v = pj[i];                     // wave-uniform broadcast
                p[4*i+0] = v.x; p[4*i+1] = v.y; p[4*i+2] = v.z; p[4*i+3] = v.w;
            }
            const int di = jt + jj;
            #pragma unroll
            for (int u = 0; u < QPL; ++u) {
                float m = cheb32_pair(qv[u], p);
                ins4p(m, di, t0[u], t1[u], t2[u], t3[u], i0[u], i1[u], i2[u]);
            }
        }
        __syncthreads();
    }
    #pragma unroll
    for (int u = 0; u < QPL; ++u) {
        int q = blockIdx.x * (TPB * QPL) + threadIdx.x + u * TPB;
        part_v[(size_t)blockIdx.y * NPTS + q] = make_float4(t0[u], t1[u], t2[u], t3[u]);
        part_i[(size_t)blockIdx.y * NPTS + q] =
            make_ushort4((unsigned short)i0[u], (unsigned short)i1[u],
                         (unsigned short)i2[u], 0);
    }
}

// ---------------------------------------------------------------------------
// K2 (fused): two-stage merge (CL compile-time -> unrolled, pipelined loads)
// + exact 3-candidate count + digamma + block-sum -> one f64 atomicAdd.
// Every point outside the joint top-3 has d_joint <= t3 = r, hence dx <= r and
// dy <= r bit-exactly (marginal max over a subset of the same f32 values).
// Index-less 4th values are safe: a split's top-3 are inserted before its 4th
// by the same thread.
// ---------------------------------------------------------------------------
template <int CL>
__global__ __launch_bounds__(TPM) void merge_check_kernel(
    const float4* __restrict__ part_v, const ushort4* __restrict__ part_i,
    const float* __restrict__ x, const float* __restrict__ y,
    double* __restrict__ acc)
{
    __shared__ float4  sv[NCHUNK][QPB_M];
    __shared__ ushort4 si[NCHUNK][QPB_M];
    const int ql = threadIdx.x & (QPB_M - 1);
    const int ck = threadIdx.x / QPB_M;          // 0..7
    const int q  = blockIdx.x * QPB_M + ql;

    float t0=-1.f,t1=-1.f,t2=-1.f,t3=-1.f;
    int i0=0,i1=0,i2=0;
    #pragma unroll
    for (int k = 0; k < CL; ++k) {
        const int s = ck * CL + k;
        float4  v  = part_v[(size_t)s * NPTS + q];
        ushort4 id = part_i[(size_t)s * NPTS + q];
        ins4p(v.x, id.x, t0,t1,t2,t3, i0,i1,i2);
        ins4p(v.y, id.y, t0,t1,t2,t3, i0,i1,i2);
        ins4p(v.z, id.z, t0,t1,t2,t3, i0,i1,i2);
        ins4p(v.w, 0,    t0,t1,t2,t3, i0,i1,i2);  // 4th: value-only
    }
    sv[ck][ql] = make_float4(t0, t1, t2, t3);
    si[ck][ql] = make_ushort4((unsigned short)i0, (unsigned short)i1,
                              (unsigned short)i2, 0);
    __syncthreads();

    if (ck == 0) {
        #pragma unroll
        for (int c = 1; c < NCHUNK; ++c) {
            float4  v  = sv[c][ql];
            ushort4 id = si[c][ql];
            ins4p(v.x, id.x, t0,t1,t2,t3, i0,i1,i2);
            ins4p(v.y, id.y, t0,t1,t2,t3, i0,i1,i2);
            ins4p(v.z, id.z, t0,t1,t2,t3, i0,i1,i2);
            ins4p(v.w, 0,    t0,t1,t2,t3, i0,i1,i2);
        }
        const float rq = t3 - 1e-15f;  // == t3 bit-exact in f32 (reference fidelity)

        float qv[32];
        load_query(qv, x, y, q);

        float vals[3] = { t0, t1, t2 };
        int   idxs[3] = { i0, i1, i2 };
        int missx = 0, missy = 0;
        #pragma unroll
        for (int k = 0; k < 3; ++k) {
            const int j = idxs[k];
            const float4* px4 = reinterpret_cast<const float4*>(x) + (size_t)j * 4;
            const float4* py4 = reinterpret_cast<const float4*>(y) + (size_t)j * 4;
            float mx = 0.0f, my = 0.0f;
            #pragma unroll
            for (int i = 0; i < 4; ++i) {
                float4 a = px4[i];
                mx = fmax3(mx, fmax3(fabsf(qv[4*i+0]-a.x), fabsf(qv[4*i+1]-a.y),
                                     fabsf(qv[4*i+2]-a.z)), fabsf(qv[4*i+3]-a.w));
                float4 b = py4[i];
                my = fmax3(my, fmax3(fabsf(qv[16+4*i+0]-b.x), fabsf(qv[16+4*i+1]-b.y),
                                     fabsf(qv[16+4*i+2]-b.z)), fabsf(qv[16+4*i+3]-b.w));
            }
            const bool act = vals[k] > rq;   // only strict-greater joints can miss
            missx += (act && (mx > rq)) ? 1 : 0;
            missy += (act && (my > rq)) ? 1 : 0;
        }
        const int nx = NPTS - missx;
        const int ny = NPTS - missy;
        double d = digamma_d((double)nx) + digamma_d((double)ny);

        // reduce across the 32 active lanes (lanes 0..31 of wave 0)
        #pragma unroll
        for (int off = 16; off > 0; off >>= 1)
            d += __shfl_down(d, off, 32);
        if (ql == 0) atomicAdd(acc, d);
    }
}

// ---------------------------------------------------------------------------
// K3: ans = psi(N) + psi(k) - acc/N  (single wave; log terms cancel exactly)
// ---------------------------------------------------------------------------
__global__ __launch_bounds__(64) void final_kernel(
    const double* __restrict__ acc, float* __restrict__ out)
{
    if (threadIdx.x == 0) {
        double ans = digamma_d((double)NPTS) + digamma_d(4.0) - acc[0] / (double)NPTS;
        out[0] = (float)ans;
    }
}

// ---------------------------------------------------------------------------
extern "C" void kernel_launch(void* const* d_in, const int* in_sizes, int n_in,
                              void* d_out, int out_size, void* d_ws, size_t ws_size,
                              hipStream_t stream)
{
    (void)in_sizes; (void)n_in; (void)out_size;
    const float* x = (const float*)d_in[0];
    const float* y = (const float*)d_in[1];
    float* out = (float*)d_out;

    // workspace: acc (1 f64, 16B slot) | part_v (Sk*NPTS float4) | part_i (Sk*NPTS ushort4)
    char* ws = (char*)d_ws;
    double* acc = (double*)ws;
    char*   p0  = ws + 16;

    int Sk = 128;
    auto need = [&](int sk) {
        return (size_t)(p0 - ws) + (size_t)sk * NPTS * 24;
    };
    while (Sk > 32 && need(Sk) > ws_size) Sk >>= 1;

    float4*  part_v = (float4*)p0;
    ushort4* part_i = (ushort4*)(p0 + (size_t)Sk * NPTS * 16);
    const int pps = NPTS / Sk;   // multiple of TILE for Sk<=128

    hipMemsetAsync(acc, 0, sizeof(double), stream);

    dim3 gridK(NPTS / (TPB * QPL), Sk);   // (16,128) = 2048 blocks = 8192 waves
    knn_part_kernel<<<gridK, TPB, 0, stream>>>(x, y, part_v, part_i, pps);
    if (Sk == 128)
        merge_check_kernel<16><<<NPTS / QPB_M, TPM, 0, stream>>>(part_v, part_i, x, y, acc);
    else if (Sk == 64)
        merge_check_kernel<8><<<NPTS / QPB_M, TPM, 0, stream>>>(part_v, part_i, x, y, acc);
    else
        merge_check_kernel<4><<<NPTS / QPB_M, TPM, 0, stream>>>(part_v, part_i, x, y, acc);
    final_kernel<<<1, 64, 0, stream>>>(acc, out);
}

// Round 12
// 100.301 us; speedup vs baseline: 1.9117x; 1.6235x over previous
//
#include <hip/hip_runtime.h>
#include <math.h>

#define NPTS 8192
#define TPB  256
#define TPM  256
#define QPB_M 32          // queries per merge block
#define NCHUNK 8          // split-chunks per merge block
#define NC_MAX 256        // padded candidate count (32 dims x 8 extremes)
#define NSPLIT 8          // candidate splits
#define CPS 32            // candidates per split

__device__ __forceinline__ float fmax3(float a, float b, float c) {
    return fmaxf(fmaxf(a, b), c);
}

// Forced v_max3_f32 with abs modifiers (R10/R11-proven bit-correct).
__device__ __forceinline__ float max3abs(float a, float b, float c) {
    float r;
    asm("v_max3_f32 %0, |%1|, |%2|, |%3|" : "=v"(r) : "v"(a), "v"(b), "v"(c));
    return r;
}
__device__ __forceinline__ float max3vaa(float m, float b, float c) {
    float r;
    asm("v_max3_f32 %0, %1, |%2|, |%3|" : "=v"(r) : "v"(m), "v"(b), "v"(c));
    return r;
}
__device__ __forceinline__ float max3v(float a, float b, float c) {
    float r;
    asm("v_max3_f32 %0, %1, %2, %3" : "=v"(r) : "v"(a), "v"(b), "v"(c));
    return r;
}

// 32-dim Chebyshev: 32 subs + 16 max3/max ops.
__device__ __forceinline__ float cheb32_pair(const float* __restrict__ q,
                                             const float* __restrict__ p) {
    float s[32];
    #pragma unroll
    for (int k = 0; k < 32; ++k) s[k] = q[k] - p[k];
    float l[10];
    #pragma unroll
    for (int g = 0; g < 10; ++g) l[g] = max3abs(s[3*g], s[3*g+1], s[3*g+2]);
    float c3 = max3vaa(l[9], s[30], s[31]);
    float c0 = max3v(l[0], l[1], l[2]);
    float c1 = max3v(l[3], l[4], l[5]);
    float c2 = max3v(l[6], l[7], l[8]);
    return fmaxf(max3v(c0, c1, c2), c3);
}

// Branchless top-4 insert, indices on levels 0-2 (R8-proven).
__device__ __forceinline__ void ins4p(float d, int di,
    float& t0, float& t1, float& t2, float& t3,
    int& i0, int& i1, int& i2)
{
    bool c0 = d > t0;
    float v1 = fminf(t0, d); int j1 = c0 ? i0 : di;
    t0 = fmaxf(t0, d);       i0 = c0 ? di : i0;
    bool c1 = v1 > t1;
    float v2 = fminf(t1, v1); int j2 = c1 ? i1 : j1;
    t1 = fmaxf(t1, v1);       i1 = c1 ? j1 : i1;
    bool c2 = v2 > t2;
    float v3 = fminf(t2, v2);
    t2 = fmaxf(t2, v2);       i2 = c2 ? j2 : i2;
    t3 = fmaxf(t3, v3);
}

// Branchless top-4 insert with indices on ALL 4 levels (for extremes).
__device__ __forceinline__ void ins4full(float d, int di,
    float& t0, float& t1, float& t2, float& t3,
    int& i0, int& i1, int& i2, int& i3)
{
    bool c0 = d > t0;
    float v1 = fminf(t0, d); int j1 = c0 ? i0 : di;
    t0 = fmaxf(t0, d);       i0 = c0 ? di : i0;
    bool c1 = v1 > t1;
    float v2 = fminf(t1, v1); int j2 = c1 ? i1 : j1;
    t1 = fmaxf(t1, v1);       i1 = c1 ? j1 : i1;
    bool c2 = v2 > t2;
    float v3 = fminf(t2, v2); int j3 = c2 ? i2 : j2;
    t2 = fmaxf(t2, v2);       i2 = c2 ? j2 : i2;
    bool c3 = v3 > t3;
    t3 = fmaxf(t3, v3);       i3 = c3 ? j3 : i3;
}

__device__ double digamma_d(double x) {
    double r = 0.0;
    while (x < 6.0) { r -= 1.0 / x; x += 1.0; }
    double f = 1.0 / (x * x);
    double t = f * (1.0/12.0 - f * (1.0/120.0 - f * (1.0/252.0 - f * (1.0/240.0 - f * (1.0/132.0)))));
    return r + log(x) - 0.5 / x - t;
}

__device__ __forceinline__ void load_query(float* qv, const float* __restrict__ x,
                                           const float* __restrict__ y, int q)
{
    const float4* qx4 = reinterpret_cast<const float4*>(x) + (size_t)q * 4;
    const float4* qy4 = reinterpret_cast<const float4*>(y) + (size_t)q * 4;
    #pragma unroll
    for (int i = 0; i < 4; ++i) {
        float4 v = qx4[i];
        qv[4*i+0] = v.x; qv[4*i+1] = v.y; qv[4*i+2] = v.z; qv[4*i+3] = v.w;
        float4 w = qy4[i];
        qv[16+4*i+0] = w.x; qv[16+4*i+1] = w.y; qv[16+4*i+2] = w.z; qv[16+4*i+3] = w.w;
    }
}

// ---------------------------------------------------------------------------
// K0: per-dim extremes. One wave per joint dim (32 dims). Each wave finds the
// 4 largest and 4 smallest values (with indices) of its dim via per-lane
// top-4 + shuffle-butterfly merge.
// THEOREM (exact): for any p and fixed q, d(q,p)=|q_k-p_k| at its argmax dim
// k. If p is not among the 4 extreme points of dim k on q's far side, then
// >=4 points (those extremes) have joint distance >= d(q,p). Hence the global
// top-4 values and top-3 indices lie in the union of per-dim 4-lowest/4-highest
// -- a query-independent candidate set of <=256 points.
// ---------------------------------------------------------------------------
__global__ __launch_bounds__(256) void extremes_kernel(
    const float* __restrict__ x, const float* __restrict__ y,
    unsigned short* __restrict__ cand_raw)
{
    const int dim  = blockIdx.x * 4 + (threadIdx.x >> 6);   // 0..31
    const int lane = threadIdx.x & 63;
    const float* base = (dim < 16) ? (x + dim) : (y + (dim - 16));

    float h0=-3.4e38f,h1=-3.4e38f,h2=-3.4e38f,h3=-3.4e38f;  // top-4 max
    int   a0=0,a1=0,a2=0,a3=0;
    float l0=-3.4e38f,l1=-3.4e38f,l2=-3.4e38f,l3=-3.4e38f;  // top-4 of (-v) = min
    int   b0=0,b1=0,b2=0,b3=0;
    #pragma unroll 4
    for (int j = lane; j < NPTS; j += 64) {
        float v = base[(size_t)j * 16];
        ins4full( v, j, h0,h1,h2,h3, a0,a1,a2,a3);
        ins4full(-v, j, l0,l1,l2,l3, b0,b1,b2,b3);
    }
    #pragma unroll
    for (int off = 32; off > 0; off >>= 1) {
        float m0=__shfl_xor(h0,off), m1=__shfl_xor(h1,off),
              m2=__shfl_xor(h2,off), m3=__shfl_xor(h3,off);
        int   c0=__shfl_xor(a0,off), c1=__shfl_xor(a1,off),
              c2=__shfl_xor(a2,off), c3=__shfl_xor(a3,off);
        ins4full(m0,c0, h0,h1,h2,h3, a0,a1,a2,a3);
        ins4full(m1,c1, h0,h1,h2,h3, a0,a1,a2,a3);
        ins4full(m2,c2, h0,h1,h2,h3, a0,a1,a2,a3);
        ins4full(m3,c3, h0,h1,h2,h3, a0,a1,a2,a3);
        float n0=__shfl_xor(l0,off), n1=__shfl_xor(l1,off),
              n2=__shfl_xor(l2,off), n3=__shfl_xor(l3,off);
        int   d0=__shfl_xor(b0,off), d1=__shfl_xor(b1,off),
              d2=__shfl_xor(b2,off), d3=__shfl_xor(b3,off);
        ins4full(n0,d0, l0,l1,l2,l3, b0,b1,b2,b3);
        ins4full(n1,d1, l0,l1,l2,l3, b0,b1,b2,b3);
        ins4full(n2,d2, l0,l1,l2,l3, b0,b1,b2,b3);
        ins4full(n3,d3, l0,l1,l2,l3, b0,b1,b2,b3);
    }
    if (lane == 0) {
        cand_raw[dim*8+0] = (unsigned short)a0;
        cand_raw[dim*8+1] = (unsigned short)a1;
        cand_raw[dim*8+2] = (unsigned short)a2;
        cand_raw[dim*8+3] = (unsigned short)a3;
        cand_raw[dim*8+4] = (unsigned short)b0;
        cand_raw[dim*8+5] = (unsigned short)b1;
        cand_raw[dim*8+6] = (unsigned short)b2;
        cand_raw[dim*8+7] = (unsigned short)b3;
    }
}

// ---------------------------------------------------------------------------
// K0b: dedupe the 256 raw candidates (a point can be extreme in several dims;
// duplicates would corrupt the top-4). LDS bitmask + compaction. Output:
// compacted prefix + 0xFFFF sentinels.
// ---------------------------------------------------------------------------
__global__ __launch_bounds__(256) void dedupe_kernel(
    const unsigned short* __restrict__ cand_raw,
    unsigned short* __restrict__ dlist)
{
    __shared__ unsigned mask[NPTS / 32];
    __shared__ unsigned short tmp[NC_MAX];
    __shared__ int cnt;
    const int tid = threadIdx.x;
    mask[tid] = 0;
    if (tid == 0) cnt = 0;
    __syncthreads();
    const int idx = cand_raw[tid];
    const unsigned bit = 1u << (idx & 31);
    unsigned old = atomicOr(&mask[idx >> 5], bit);
    if (!(old & bit)) { int p = atomicAdd(&cnt, 1); tmp[p] = (unsigned short)idx; }
    __syncthreads();
    dlist[tid] = (tid < cnt) ? tmp[tid] : (unsigned short)0xFFFF;
}

// ---------------------------------------------------------------------------
// K1: exact top-4 values + top-3 indices per query over the candidate set.
// grid (NPTS/TPB, NSPLIT); split's 32 candidates staged in LDS.
// ---------------------------------------------------------------------------
__global__ __launch_bounds__(TPB, 2) void knn_cand_kernel(
    const float* __restrict__ x, const float* __restrict__ y,
    const unsigned short* __restrict__ dlist,
    float4* __restrict__ part_v, ushort4* __restrict__ part_i)
{
    __shared__ float pc[CPS * 32];
    __shared__ unsigned short scidx[CPS];
    const int tid = threadIdx.x;
    if (tid < CPS) scidx[tid] = dlist[blockIdx.y * CPS + tid];
    __syncthreads();
    #pragma unroll
    for (int it = 0; it < (CPS * 32) / TPB; ++it) {
        int e = it * TPB + tid;
        int cand = e >> 5, dim = e & 31;
        int ci = scidx[cand];
        int j = (ci == 0xFFFF) ? 0 : ci;
        pc[e] = (dim < 16) ? x[(size_t)j * 16 + dim] : y[(size_t)j * 16 + dim - 16];
    }
    const int q = blockIdx.x * TPB + tid;
    float qv[32];
    load_query(qv, x, y, q);
    float t0=-1.f,t1=-1.f,t2=-1.f,t3=-1.f;
    int i0=0,i1=0,i2=0;
    __syncthreads();
    for (int jj = 0; jj < CPS; ++jj) {
        int ci = scidx[jj];                   // block-uniform
        if (ci == 0xFFFF) break;              // compacted: prefix property holds
        float m = cheb32_pair(qv, pc + jj * 32);
        ins4p(m, ci, t0, t1, t2, t3, i0, i1, i2);
    }
    part_v[(size_t)blockIdx.y * NPTS + q] = make_float4(t0, t1, t2, t3);
    part_i[(size_t)blockIdx.y * NPTS + q] =
        make_ushort4((unsigned short)i0, (unsigned short)i1, (unsigned short)i2, 0);
}

// ---------------------------------------------------------------------------
// K2 (R11-proven): two-stage merge + exact 3-candidate count + digamma +
// block-sum -> one f64 atomicAdd. Every point outside the joint top-3 has
// d_joint <= t3 = r, hence dx <= r and dy <= r bit-exactly.
// ---------------------------------------------------------------------------
template <int CL>
__global__ __launch_bounds__(TPM) void merge_check_kernel(
    const float4* __restrict__ part_v, const ushort4* __restrict__ part_i,
    const float* __restrict__ x, const float* __restrict__ y,
    double* __restrict__ acc)
{
    __shared__ float4  sv[NCHUNK][QPB_M];
    __shared__ ushort4 si[NCHUNK][QPB_M];
    const int ql = threadIdx.x & (QPB_M - 1);
    const int ck = threadIdx.x / QPB_M;          // 0..7
    const int q  = blockIdx.x * QPB_M + ql;

    float t0=-1.f,t1=-1.f,t2=-1.f,t3=-1.f;
    int i0=0,i1=0,i2=0;
    #pragma unroll
    for (int k = 0; k < CL; ++k) {
        const int s = ck * CL + k;
        float4  v  = part_v[(size_t)s * NPTS + q];
        ushort4 id = part_i[(size_t)s * NPTS + q];
        ins4p(v.x, id.x, t0,t1,t2,t3, i0,i1,i2);
        ins4p(v.y, id.y, t0,t1,t2,t3, i0,i1,i2);
        ins4p(v.z, id.z, t0,t1,t2,t3, i0,i1,i2);
        ins4p(v.w, 0,    t0,t1,t2,t3, i0,i1,i2);  // 4th: value-only (safe)
    }
    sv[ck][ql] = make_float4(t0, t1, t2, t3);
    si[ck][ql] = make_ushort4((unsigned short)i0, (unsigned short)i1,
                              (unsigned short)i2, 0);
    __syncthreads();

    if (ck == 0) {
        #pragma unroll
        for (int c = 1; c < NCHUNK; ++c) {
            float4  v  = sv[c][ql];
            ushort4 id = si[c][ql];
            ins4p(v.x, id.x, t0,t1,t2,t3, i0,i1,i2);
            ins4p(v.y, id.y, t0,t1,t2,t3, i0,i1,i2);
            ins4p(v.z, id.z, t0,t1,t2,t3, i0,i1,i2);
            ins4p(v.w, 0,    t0,t1,t2,t3, i0,i1,i2);
        }
        const float rq = t3 - 1e-15f;  // == t3 bit-exact in f32 (reference fidelity)

        float qv[32];
        load_query(qv, x, y, q);

        float vals[3] = { t0, t1, t2 };
        int   idxs[3] = { i0, i1, i2 };
        int missx = 0, missy = 0;
        #pragma unroll
        for (int k = 0; k < 3; ++k) {
            const int j = idxs[k];
            const float4* px4 = reinterpret_cast<const float4*>(x) + (size_t)j * 4;
            const float4* py4 = reinterpret_cast<const float4*>(y) + (size_t)j * 4;
            float mx = 0.0f, my = 0.0f;
            #pragma unroll
            for (int i = 0; i < 4; ++i) {
                float4 a = px4[i];
                mx = fmax3(mx, fmax3(fabsf(qv[4*i+0]-a.x), fabsf(qv[4*i+1]-a.y),
                                     fabsf(qv[4*i+2]-a.z)), fabsf(qv[4*i+3]-a.w));
                float4 b = py4[i];
                my = fmax3(my, fmax3(fabsf(qv[16+4*i+0]-b.x), fabsf(qv[16+4*i+1]-b.y),
                                     fabsf(qv[16+4*i+2]-b.z)), fabsf(qv[16+4*i+3]-b.w));
            }
            const bool act = vals[k] > rq;   // only strict-greater joints can miss
            missx += (act && (mx > rq)) ? 1 : 0;
            missy += (act && (my > rq)) ? 1 : 0;
        }
        const int nx = NPTS - missx;
        const int ny = NPTS - missy;
        double d = digamma_d((double)nx) + digamma_d((double)ny);
        #pragma unroll
        for (int off = 16; off > 0; off >>= 1)
            d += __shfl_down(d, off, 32);
        if (ql == 0) atomicAdd(acc, d);
    }
}

// ---------------------------------------------------------------------------
// K3: ans = psi(N) + psi(k) - acc/N  (log terms cancel exactly)
// ---------------------------------------------------------------------------
__global__ __launch_bounds__(64) void final_kernel(
    const double* __restrict__ acc, float* __restrict__ out)
{
    if (threadIdx.x == 0) {
        double ans = digamma_d((double)NPTS) + digamma_d(4.0) - acc[0] / (double)NPTS;
        out[0] = (float)ans;
    }
}

// ---------------------------------------------------------------------------
extern "C" void kernel_launch(void* const* d_in, const int* in_sizes, int n_in,
                              void* d_out, int out_size, void* d_ws, size_t ws_size,
                              hipStream_t stream)
{
    (void)in_sizes; (void)n_in; (void)out_size; (void)ws_size;
    const float* x = (const float*)d_in[0];
    const float* y = (const float*)d_in[1];
    float* out = (float*)d_out;

    // workspace: acc f64 @0 (16B) | cand_raw 256 u16 @16 | dlist 256 u16 @528
    //            | part_v [NSPLIT][NPTS] float4 @1040 | part_i ushort4 after
    char* ws = (char*)d_ws;
    double* acc = (double*)ws;
    unsigned short* cand_raw = (unsigned short*)(ws + 16);
    unsigned short* dlist    = (unsigned short*)(ws + 528);
    float4*  part_v = (float4*)(ws + 1040);
    ushort4* part_i = (ushort4*)(ws + 1040 + (size_t)NSPLIT * NPTS * 16);

    hipMemsetAsync(acc, 0, sizeof(double), stream);
    extremes_kernel<<<8, 256, 0, stream>>>(x, y, cand_raw);
    dedupe_kernel<<<1, 256, 0, stream>>>(cand_raw, dlist);
    knn_cand_kernel<<<dim3(NPTS / TPB, NSPLIT), TPB, 0, stream>>>(x, y, dlist,
                                                                  part_v, part_i);
    merge_check_kernel<1><<<NPTS / QPB_M, TPM, 0, stream>>>(part_v, part_i, x, y, acc);
    final_kernel<<<1, 64, 0, stream>>>(acc, out);
}

// Round 13
// 87.701 us; speedup vs baseline: 2.1864x; 1.1437x over previous
//
#include <hip/hip_runtime.h>
#include <math.h>

#define NPTS 8192
#define TPB  256
#define TPM  256
#define QPB_M 32          // queries per merge block
#define NCHUNK 8          // split-chunks per merge block
#define NC_MAX 256        // padded candidate count (32 dims x 8 extremes)
#define NSPLIT 8          // candidate splits
#define CPS 32            // candidates per split

__device__ __forceinline__ float fmax3(float a, float b, float c) {
    return fmaxf(fmaxf(a, b), c);
}

// Forced v_max3_f32 with abs modifiers (R10/R11-proven bit-correct).
__device__ __forceinline__ float max3abs(float a, float b, float c) {
    float r;
    asm("v_max3_f32 %0, |%1|, |%2|, |%3|" : "=v"(r) : "v"(a), "v"(b), "v"(c));
    return r;
}
__device__ __forceinline__ float max3vaa(float m, float b, float c) {
    float r;
    asm("v_max3_f32 %0, %1, |%2|, |%3|" : "=v"(r) : "v"(m), "v"(b), "v"(c));
    return r;
}
__device__ __forceinline__ float max3v(float a, float b, float c) {
    float r;
    asm("v_max3_f32 %0, %1, %2, %3" : "=v"(r) : "v"(a), "v"(b), "v"(c));
    return r;
}

// 32-dim Chebyshev: 32 subs + 16 max3/max ops.
__device__ __forceinline__ float cheb32_pair(const float* __restrict__ q,
                                             const float* __restrict__ p) {
    float s[32];
    #pragma unroll
    for (int k = 0; k < 32; ++k) s[k] = q[k] - p[k];
    float l[10];
    #pragma unroll
    for (int g = 0; g < 10; ++g) l[g] = max3abs(s[3*g], s[3*g+1], s[3*g+2]);
    float c3 = max3vaa(l[9], s[30], s[31]);
    float c0 = max3v(l[0], l[1], l[2]);
    float c1 = max3v(l[3], l[4], l[5]);
    float c2 = max3v(l[6], l[7], l[8]);
    return fmaxf(max3v(c0, c1, c2), c3);
}

// Branchless top-4 insert, indices on levels 0-2 (R8-proven).
__device__ __forceinline__ void ins4p(float d, int di,
    float& t0, float& t1, float& t2, float& t3,
    int& i0, int& i1, int& i2)
{
    bool c0 = d > t0;
    float v1 = fminf(t0, d); int j1 = c0 ? i0 : di;
    t0 = fmaxf(t0, d);       i0 = c0 ? di : i0;
    bool c1 = v1 > t1;
    float v2 = fminf(t1, v1); int j2 = c1 ? i1 : j1;
    t1 = fmaxf(t1, v1);       i1 = c1 ? j1 : i1;
    bool c2 = v2 > t2;
    float v3 = fminf(t2, v2);
    t2 = fmaxf(t2, v2);       i2 = c2 ? j2 : i2;
    t3 = fmaxf(t3, v3);
}

// Branchless top-4 insert with indices on ALL 4 levels (for extremes).
__device__ __forceinline__ void ins4full(float d, int di,
    float& t0, float& t1, float& t2, float& t3,
    int& i0, int& i1, int& i2, int& i3)
{
    bool c0 = d > t0;
    float v1 = fminf(t0, d); int j1 = c0 ? i0 : di;
    t0 = fmaxf(t0, d);       i0 = c0 ? di : i0;
    bool c1 = v1 > t1;
    float v2 = fminf(t1, v1); int j2 = c1 ? i1 : j1;
    t1 = fmaxf(t1, v1);       i1 = c1 ? j1 : i1;
    bool c2 = v2 > t2;
    float v3 = fminf(t2, v2); int j3 = c2 ? i2 : j2;
    t2 = fmaxf(t2, v2);       i2 = c2 ? j2 : i2;
    bool c3 = v3 > t3;
    t3 = fmaxf(t3, v3);       i3 = c3 ? j3 : i3;
}

__device__ double digamma_d(double x) {
    double r = 0.0;
    while (x < 6.0) { r -= 1.0 / x; x += 1.0; }
    double f = 1.0 / (x * x);
    double t = f * (1.0/12.0 - f * (1.0/120.0 - f * (1.0/252.0 - f * (1.0/240.0 - f * (1.0/132.0)))));
    return r + log(x) - 0.5 / x - t;
}

__device__ __forceinline__ void load_query(float* qv, const float* __restrict__ x,
                                           const float* __restrict__ y, int q)
{
    const float4* qx4 = reinterpret_cast<const float4*>(x) + (size_t)q * 4;
    const float4* qy4 = reinterpret_cast<const float4*>(y) + (size_t)q * 4;
    #pragma unroll
    for (int i = 0; i < 4; ++i) {
        float4 v = qx4[i];
        qv[4*i+0] = v.x; qv[4*i+1] = v.y; qv[4*i+2] = v.z; qv[4*i+3] = v.w;
        float4 w = qy4[i];
        qv[16+4*i+0] = w.x; qv[16+4*i+1] = w.y; qv[16+4*i+2] = w.z; qv[16+4*i+3] = w.w;
    }
}

// ---------------------------------------------------------------------------
// K0: per-dim extremes. ONE BLOCK PER DIM (32 blocks x 256 threads): each
// thread strides 32 points (unrolled -> pipelined loads), intra-wave
// shuffle-butterfly, then tiny LDS cross-wave merge. (R12's 8-block version
// was latency-bound at 40.5 us: 32 waves, 128 serial loads/lane.)
// THEOREM (exact, R12-validated absmax 0.0): the global top-4 values and
// top-3 indices lie in the union of per-dim 4-lowest/4-highest points.
// ---------------------------------------------------------------------------
__global__ __launch_bounds__(256) void extremes_kernel(
    const float* __restrict__ x, const float* __restrict__ y,
    unsigned short* __restrict__ cand_raw)
{
    const int dim  = blockIdx.x;             // 0..31
    const int tid  = threadIdx.x;
    const int lane = tid & 63;
    const int wave = tid >> 6;               // 0..3
    const float* base = (dim < 16) ? (x + dim) : (y + (dim - 16));

    float h0=-3.4e38f,h1=-3.4e38f,h2=-3.4e38f,h3=-3.4e38f;  // top-4 max
    int   a0=0,a1=0,a2=0,a3=0;
    float l0=-3.4e38f,l1=-3.4e38f,l2=-3.4e38f,l3=-3.4e38f;  // top-4 of (-v) = min
    int   b0=0,b1=0,b2=0,b3=0;
    #pragma unroll 8
    for (int j = tid; j < NPTS; j += 256) {
        float v = base[(size_t)j * 16];
        ins4full( v, j, h0,h1,h2,h3, a0,a1,a2,a3);
        ins4full(-v, j, l0,l1,l2,l3, b0,b1,b2,b3);
    }
    #pragma unroll
    for (int off = 32; off > 0; off >>= 1) {
        float m0=__shfl_xor(h0,off), m1=__shfl_xor(h1,off),
              m2=__shfl_xor(h2,off), m3=__shfl_xor(h3,off);
        int   c0=__shfl_xor(a0,off), c1=__shfl_xor(a1,off),
              c2=__shfl_xor(a2,off), c3=__shfl_xor(a3,off);
        ins4full(m0,c0, h0,h1,h2,h3, a0,a1,a2,a3);
        ins4full(m1,c1, h0,h1,h2,h3, a0,a1,a2,a3);
        ins4full(m2,c2, h0,h1,h2,h3, a0,a1,a2,a3);
        ins4full(m3,c3, h0,h1,h2,h3, a0,a1,a2,a3);
        float n0=__shfl_xor(l0,off), n1=__shfl_xor(l1,off),
              n2=__shfl_xor(l2,off), n3=__shfl_xor(l3,off);
        int   d0=__shfl_xor(b0,off), d1=__shfl_xor(b1,off),
              d2=__shfl_xor(b2,off), d3=__shfl_xor(b3,off);
        ins4full(n0,d0, l0,l1,l2,l3, b0,b1,b2,b3);
        ins4full(n1,d1, l0,l1,l2,l3, b0,b1,b2,b3);
        ins4full(n2,d2, l0,l1,l2,l3, b0,b1,b2,b3);
        ins4full(n3,d3, l0,l1,l2,l3, b0,b1,b2,b3);
    }
    __shared__ float shv[4][8];
    __shared__ int   shi[4][8];
    if (lane == 0) {
        shv[wave][0]=h0; shv[wave][1]=h1; shv[wave][2]=h2; shv[wave][3]=h3;
        shv[wave][4]=l0; shv[wave][5]=l1; shv[wave][6]=l2; shv[wave][7]=l3;
        shi[wave][0]=a0; shi[wave][1]=a1; shi[wave][2]=a2; shi[wave][3]=a3;
        shi[wave][4]=b0; shi[wave][5]=b1; shi[wave][6]=b2; shi[wave][7]=b3;
    }
    __syncthreads();
    if (tid == 0) {
        #pragma unroll
        for (int w = 1; w < 4; ++w) {
            #pragma unroll
            for (int e = 0; e < 4; ++e) {
                ins4full(shv[w][e],   shi[w][e],   h0,h1,h2,h3, a0,a1,a2,a3);
                ins4full(shv[w][4+e], shi[w][4+e], l0,l1,l2,l3, b0,b1,b2,b3);
            }
        }
        cand_raw[dim*8+0] = (unsigned short)a0;
        cand_raw[dim*8+1] = (unsigned short)a1;
        cand_raw[dim*8+2] = (unsigned short)a2;
        cand_raw[dim*8+3] = (unsigned short)a3;
        cand_raw[dim*8+4] = (unsigned short)b0;
        cand_raw[dim*8+5] = (unsigned short)b1;
        cand_raw[dim*8+6] = (unsigned short)b2;
        cand_raw[dim*8+7] = (unsigned short)b3;
    }
}

// ---------------------------------------------------------------------------
// K0b: dedupe the 256 raw candidates. LDS bitmask + compaction.
// Output: compacted prefix + 0xFFFF sentinels. (R12-proven)
// ---------------------------------------------------------------------------
__global__ __launch_bounds__(256) void dedupe_kernel(
    const unsigned short* __restrict__ cand_raw,
    unsigned short* __restrict__ dlist)
{
    __shared__ unsigned mask[NPTS / 32];
    __shared__ unsigned short tmp[NC_MAX];
    __shared__ int cnt;
    const int tid = threadIdx.x;
    mask[tid] = 0;
    if (tid == 0) cnt = 0;
    __syncthreads();
    const int idx = cand_raw[tid];
    const unsigned bit = 1u << (idx & 31);
    unsigned old = atomicOr(&mask[idx >> 5], bit);
    if (!(old & bit)) { int p = atomicAdd(&cnt, 1); tmp[p] = (unsigned short)idx; }
    __syncthreads();
    dlist[tid] = (tid < cnt) ? tmp[tid] : (unsigned short)0xFFFF;
}

// ---------------------------------------------------------------------------
// K1: exact top-4 values + top-3 indices per query over the candidate set.
// grid (NPTS/TPB, NSPLIT); split's 32 candidates staged in LDS. (R12-proven)
// ---------------------------------------------------------------------------
__global__ __launch_bounds__(TPB, 2) void knn_cand_kernel(
    const float* __restrict__ x, const float* __restrict__ y,
    const unsigned short* __restrict__ dlist,
    float4* __restrict__ part_v, ushort4* __restrict__ part_i)
{
    __shared__ float pc[CPS * 32];
    __shared__ unsigned short scidx[CPS];
    const int tid = threadIdx.x;
    if (tid < CPS) scidx[tid] = dlist[blockIdx.y * CPS + tid];
    __syncthreads();
    #pragma unroll
    for (int it = 0; it < (CPS * 32) / TPB; ++it) {
        int e = it * TPB + tid;
        int cand = e >> 5, dim = e & 31;
        int ci = scidx[cand];
        int j = (ci == 0xFFFF) ? 0 : ci;
        pc[e] = (dim < 16) ? x[(size_t)j * 16 + dim] : y[(size_t)j * 16 + dim - 16];
    }
    const int q = blockIdx.x * TPB + tid;
    float qv[32];
    load_query(qv, x, y, q);
    float t0=-1.f,t1=-1.f,t2=-1.f,t3=-1.f;
    int i0=0,i1=0,i2=0;
    __syncthreads();
    for (int jj = 0; jj < CPS; ++jj) {
        int ci = scidx[jj];                   // block-uniform
        if (ci == 0xFFFF) break;              // compacted: prefix property holds
        float m = cheb32_pair(qv, pc + jj * 32);
        ins4p(m, ci, t0, t1, t2, t3, i0, i1, i2);
    }
    part_v[(size_t)blockIdx.y * NPTS + q] = make_float4(t0, t1, t2, t3);
    part_i[(size_t)blockIdx.y * NPTS + q] =
        make_ushort4((unsigned short)i0, (unsigned short)i1, (unsigned short)i2, 0);
}

// ---------------------------------------------------------------------------
// K2 (R11-proven): two-stage merge + exact 3-candidate count + digamma +
// block-sum -> one f64 atomicAdd. Every point outside the joint top-3 has
// d_joint <= t3 = r, hence dx <= r and dy <= r bit-exactly.
// ---------------------------------------------------------------------------
template <int CL>
__global__ __launch_bounds__(TPM) void merge_check_kernel(
    const float4* __restrict__ part_v, const ushort4* __restrict__ part_i,
    const float* __restrict__ x, const float* __restrict__ y,
    double* __restrict__ acc)
{
    __shared__ float4  sv[NCHUNK][QPB_M];
    __shared__ ushort4 si[NCHUNK][QPB_M];
    const int ql = threadIdx.x & (QPB_M - 1);
    const int ck = threadIdx.x / QPB_M;          // 0..7
    const int q  = blockIdx.x * QPB_M + ql;

    float t0=-1.f,t1=-1.f,t2=-1.f,t3=-1.f;
    int i0=0,i1=0,i2=0;
    #pragma unroll
    for (int k = 0; k < CL; ++k) {
        const int s = ck * CL + k;
        float4  v  = part_v[(size_t)s * NPTS + q];
        ushort4 id = part_i[(size_t)s * NPTS + q];
        ins4p(v.x, id.x, t0,t1,t2,t3, i0,i1,i2);
        ins4p(v.y, id.y, t0,t1,t2,t3, i0,i1,i2);
        ins4p(v.z, id.z, t0,t1,t2,t3, i0,i1,i2);
        ins4p(v.w, 0,    t0,t1,t2,t3, i0,i1,i2);  // 4th: value-only (safe)
    }
    sv[ck][ql] = make_float4(t0, t1, t2, t3);
    si[ck][ql] = make_ushort4((unsigned short)i0, (unsigned short)i1,
                              (unsigned short)i2, 0);
    __syncthreads();

    if (ck == 0) {
        #pragma unroll
        for (int c = 1; c < NCHUNK; ++c) {
            float4  v  = sv[c][ql];
            ushort4 id = si[c][ql];
            ins4p(v.x, id.x, t0,t1,t2,t3, i0,i1,i2);
            ins4p(v.y, id.y, t0,t1,t2,t3, i0,i1,i2);
            ins4p(v.z, id.z, t0,t1,t2,t3, i0,i1,i2);
            ins4p(v.w, 0,    t0,t1,t2,t3, i0,i1,i2);
        }
        const float rq = t3 - 1e-15f;  // == t3 bit-exact in f32 (reference fidelity)

        float qv[32];
        load_query(qv, x, y, q);

        float vals[3] = { t0, t1, t2 };
        int   idxs[3] = { i0, i1, i2 };
        int missx = 0, missy = 0;
        #pragma unroll
        for (int k = 0; k < 3; ++k) {
            const int j = idxs[k];
            const float4* px4 = reinterpret_cast<const float4*>(x) + (size_t)j * 4;
            const float4* py4 = reinterpret_cast<const float4*>(y) + (size_t)j * 4;
            float mx = 0.0f, my = 0.0f;
            #pragma unroll
            for (int i = 0; i < 4; ++i) {
                float4 a = px4[i];
                mx = fmax3(mx, fmax3(fabsf(qv[4*i+0]-a.x), fabsf(qv[4*i+1]-a.y),
                                     fabsf(qv[4*i+2]-a.z)), fabsf(qv[4*i+3]-a.w));
                float4 b = py4[i];
                my = fmax3(my, fmax3(fabsf(qv[16+4*i+0]-b.x), fabsf(qv[16+4*i+1]-b.y),
                                     fabsf(qv[16+4*i+2]-b.z)), fabsf(qv[16+4*i+3]-b.w));
            }
            const bool act = vals[k] > rq;   // only strict-greater joints can miss
            missx += (act && (mx > rq)) ? 1 : 0;
            missy += (act && (my > rq)) ? 1 : 0;
        }
        const int nx = NPTS - missx;
        const int ny = NPTS - missy;
        double d = digamma_d((double)nx) + digamma_d((double)ny);
        #pragma unroll
        for (int off = 16; off > 0; off >>= 1)
            d += __shfl_down(d, off, 32);
        if (ql == 0) atomicAdd(acc, d);
    }
}

// ---------------------------------------------------------------------------
// K3: ans = psi(N) + psi(k) - acc/N  (log terms cancel exactly)
// ---------------------------------------------------------------------------
__global__ __launch_bounds__(64) void final_kernel(
    const double* __restrict__ acc, float* __restrict__ out)
{
    if (threadIdx.x == 0) {
        double ans = digamma_d((double)NPTS) + digamma_d(4.0) - acc[0] / (double)NPTS;
        out[0] = (float)ans;
    }
}

// ---------------------------------------------------------------------------
extern "C" void kernel_launch(void* const* d_in, const int* in_sizes, int n_in,
                              void* d_out, int out_size, void* d_ws, size_t ws_size,
                              hipStream_t stream)
{
    (void)in_sizes; (void)n_in; (void)out_size; (void)ws_size;
    const float* x = (const float*)d_in[0];
    const float* y = (const float*)d_in[1];
    float* out = (float*)d_out;

    // workspace: acc f64 @0 (16B) | cand_raw 256 u16 @16 | dlist 256 u16 @528
    //            | part_v [NSPLIT][NPTS] float4 @1040 | part_i ushort4 after
    char* ws = (char*)d_ws;
    double* acc = (double*)ws;
    unsigned short* cand_raw = (unsigned short*)(ws + 16);
    unsigned short* dlist    = (unsigned short*)(ws + 528);
    float4*  part_v = (float4*)(ws + 1040);
    ushort4* part_i = (ushort4*)(ws + 1040 + (size_t)NSPLIT * NPTS * 16);

    hipMemsetAsync(acc, 0, sizeof(double), stream);
    extremes_kernel<<<32, 256, 0, stream>>>(x, y, cand_raw);
    dedupe_kernel<<<1, 256, 0, stream>>>(cand_raw, dlist);
    knn_cand_kernel<<<dim3(NPTS / TPB, NSPLIT), TPB, 0, stream>>>(x, y, dlist,
                                                                  part_v, part_i);
    merge_check_kernel<1><<<NPTS / QPB_M, TPM, 0, stream>>>(part_v, part_i, x, y, acc);
    final_kernel<<<1, 64, 0, stream>>>(acc, out);
}